// Round 10
// baseline (59.560 us; speedup 1.0000x reference)
//
#include <hip/hip_runtime.h>

#define SEQ 512
#define EMB 768
#define K3E 2304
#define DHD 48

// ============================================================================
// K0: pun[128,768] = masked gather-mean of lhs rows; zeroes the 4 attn->final
// flags (re-armed every call: deterministic across graph replays). 96 x 256.
// ============================================================================
__global__ __launch_bounds__(256) void k0_pun(
    const float* __restrict__ lhs, const int* __restrict__ loc,
    float* __restrict__ pun, int* __restrict__ flags)
{
  if (blockIdx.x == 0 && threadIdx.x < 4)
    __hip_atomic_store(&flags[threadIdx.x], 0, __ATOMIC_RELAXED,
                       __HIP_MEMORY_SCOPE_AGENT);
  int id = blockIdx.x * 256 + threadIdx.x;   // 24576 = 128 * 192
  int row = id / 192;
  int ch  = id - row * 192;
  int cnt = 0;
  float4 s = make_float4(0.f, 0.f, 0.f, 0.f);
#pragma unroll
  for (int j = 0; j < 5; j++) {
    int v = loc[row * 5 + j];
    if (v >= 0) {
      float4 wv = *(const float4*)&lhs[((size_t)row * SEQ + v) * EMB + ch * 4];
      s.x += wv.x; s.y += wv.y; s.z += wv.z; s.w += wv.w;
      cnt++;
    }
  }
  float inv = 1.0f / (float)cnt;
  *(float4*)&pun[(size_t)row * EMB + ch * 4] =
      make_float4(s.x * inv, s.y * inv, s.z * inv, s.w * inv);
}

// ============================================================================
// K1 (R5-verbatim, best measured): blocks 0..575 proj GEMM (16x32), blocks
// 576..743 W_comb (16x32), block 744 bias_comb. 512 thr = 8 waves, wave-
// private K=96 (6 steps BK=16), dbuf LDS, zero K-loop barriers, 2x4 microtile.
// ============================================================================
__global__ __launch_bounds__(512, 4) void k1_gemm_wcomb(
    const float* __restrict__ pun, const float* __restrict__ Bw,
    const float* __restrict__ bias, float* __restrict__ C,
    const float* __restrict__ wlin, const float* __restrict__ wout,
    const float* __restrict__ bout, const float* __restrict__ blin,
    float* __restrict__ wcomb, float* __restrict__ wsbias)
{
  __shared__ float lds[14336];
  const int t = threadIdx.x;
  const int w = t >> 6, l = t & 63;
  const int tx = l & 7, ty = l >> 3;     // frag: n=tx*4, m=ty*2
  const int gm = l & 15, gq = l >> 4;    // A-staging: row, k-quad
  const int bl = l & 31, bh = l >> 5;    // B-staging: row, k-half
  const int kbase = w * 96;
  const int AW = w * 1792, BW = AW + 640;

  float4 aF, bF0, bF1;
  float acc[2][4] = {};

#define STAGE_A(b) {                                                         \
    int Ab = AW + (b) * 320;                                                 \
    lds[Ab + (gq*4+0)*20 + gm] = aF.x;                                       \
    lds[Ab + (gq*4+1)*20 + gm] = aF.y;                                       \
    lds[Ab + (gq*4+2)*20 + gm] = aF.z;                                       \
    lds[Ab + (gq*4+3)*20 + gm] = aF.w; }

#define INNER(b) {                                                           \
    int Ab = AW + (b) * 320, Bb = BW + (b) * 576;                            \
    _Pragma("unroll")                                                        \
    for (int kk = 0; kk < 16; kk++) {                                        \
      float2 a  = *(float2*)&lds[Ab + kk * 20 + ty * 2];                     \
      float4 bb = *(float4*)&lds[Bb + kk * 36 + tx * 4];                     \
      acc[0][0] += a.x*bb.x; acc[0][1] += a.x*bb.y;                          \
      acc[0][2] += a.x*bb.z; acc[0][3] += a.x*bb.w;                          \
      acc[1][0] += a.y*bb.x; acc[1][1] += a.y*bb.y;                          \
      acc[1][2] += a.y*bb.z; acc[1][3] += a.y*bb.w;                          \
    } }

  if (blockIdx.x < 576) {
    const int c  = blockIdx.x;
    const int bm = (c / 72) * 16, bn = (c % 72) * 32;
    const float* arow = pun + (size_t)(bm + gm) * EMB;
    const float* brow = Bw + (size_t)(bn + bl) * EMB;

#define G_LOAD(s) {                                                          \
    int k0 = kbase + (s) * 16;                                               \
    aF  = *(const float4*)&arow[k0 + gq * 4];                                \
    bF0 = *(const float4*)&brow[k0 + bh * 8 + 0];                            \
    bF1 = *(const float4*)&brow[k0 + bh * 8 + 4]; }

#define G_WRITE(b) {                                                         \
    STAGE_A(b)                                                               \
    int Bb = BW + (b) * 576;                                                 \
    lds[Bb + (bh*8+0)*36 + bl] = bF0.x; lds[Bb + (bh*8+1)*36 + bl] = bF0.y;  \
    lds[Bb + (bh*8+2)*36 + bl] = bF0.z; lds[Bb + (bh*8+3)*36 + bl] = bF0.w;  \
    lds[Bb + (bh*8+4)*36 + bl] = bF1.x; lds[Bb + (bh*8+5)*36 + bl] = bF1.y;  \
    lds[Bb + (bh*8+6)*36 + bl] = bF1.z; lds[Bb + (bh*8+7)*36 + bl] = bF1.w; }

    G_LOAD(0); G_WRITE(0);
    for (int s = 0; s < 6; s++) {
      int b = s & 1;
      if (s < 5) G_LOAD(s + 1);
      INNER(b);
      if (s < 5) G_WRITE(b ^ 1);
    }
#undef G_LOAD
#undef G_WRITE
#pragma unroll
    for (int i = 0; i < 2; i++)
      *(float4*)&lds[AW + (ty*2 + i) * 32 + tx * 4] =
          make_float4(acc[i][0], acc[i][1], acc[i][2], acc[i][3]);
    __syncthreads();
    int m = t >> 5, n = t & 31;
    float v = lds[0*1792 + t] + lds[1*1792 + t] + lds[2*1792 + t] + lds[3*1792 + t]
            + lds[4*1792 + t] + lds[5*1792 + t] + lds[6*1792 + t] + lds[7*1792 + t]
            + bias[bn + n];
    C[(size_t)(bm + m) * K3E + bn + n] = v;
  } else if (blockIdx.x < 744) {
    const int cc = blockIdx.x - 576;
    const int bm = (cc / 24) * 16, bn = (cc % 24) * 32;
    const int wi = l >> 2;
    const int j4 = (l & 3) * 8;
    int arow_i = bm + gm; if (arow_i > 99) arow_i = 99;
    const float* arow = wlin + (size_t)arow_i * EMB;

#define W_LOAD(s) {                                                          \
    int k0 = kbase + (s) * 16;                                               \
    aF  = *(const float4*)&arow[k0 + gq * 4];                                \
    const float* wr = wout + (size_t)(k0 + wi) * EMB + bn + j4;              \
    bF0 = *(const float4*)&wr[0];                                            \
    bF1 = *(const float4*)&wr[4]; }

#define W_WRITE(b) {                                                         \
    STAGE_A(b)                                                               \
    int Bb = BW + (b) * 576;                                                 \
    *(float4*)&lds[Bb + wi*36 + j4]     = bF0;                               \
    *(float4*)&lds[Bb + wi*36 + j4 + 4] = bF1; }

    W_LOAD(0); W_WRITE(0);
    for (int s = 0; s < 6; s++) {
      int b = s & 1;
      if (s < 5) W_LOAD(s + 1);
      INNER(b);
      if (s < 5) W_WRITE(b ^ 1);
    }
#undef W_LOAD
#undef W_WRITE
#pragma unroll
    for (int i = 0; i < 2; i++)
      *(float4*)&lds[AW + (ty*2 + i) * 32 + tx * 4] =
          make_float4(acc[i][0], acc[i][1], acc[i][2], acc[i][3]);
    __syncthreads();
    int m = t >> 5, n = t & 31;
    if (bm + m < 100) {
      float v = lds[0*1792 + t] + lds[1*1792 + t] + lds[2*1792 + t] + lds[3*1792 + t]
              + lds[4*1792 + t] + lds[5*1792 + t] + lds[6*1792 + t] + lds[7*1792 + t];
      wcomb[(size_t)(bm + m) * EMB + bn + n] = v;
    }
  } else {
    if (t < 400) {
      int col = t >> 2, q = t & 3;
      const float* wr = wlin + (size_t)col * EMB + q * 192;
      const float* br = bout + q * 192;
      float p = 0.f;
#pragma unroll
      for (int j = 0; j < 48; j++) {
        float4 wv = *(const float4*)&wr[j * 4];
        float4 bv = *(const float4*)&br[j * 4];
        p += wv.x*bv.x + wv.y*bv.y + wv.z*bv.z + wv.w*bv.w;
      }
      p += __shfl_xor(p, 1); p += __shfl_xor(p, 2);
      if (q == 0) wsbias[col] = p + blin[col];
    }
  }
#undef STAGE_A
#undef INNER
}

// ============================================================================
// K23: blocks 0..63  = attention (R6-P2-verified 512-thr body: h = bx>>2,
//                      32-row l-tile), ending with fence + flag arrival.
//      blocks 64..95 = final GEMM (R8-verified body), spinning on its
//                      l-tile's flag (16 head arrivals) before starting.
// 96 blocks total -> all resident regardless of dispatch order (no deadlock).
// ============================================================================
__global__ __launch_bounds__(512, 4) void k23_attn_final(
    const float* __restrict__ proj, const float* __restrict__ wcomb,
    const float* __restrict__ wsbias, float* __restrict__ ctx,
    float* __restrict__ out, int* __restrict__ flags)
{
  __shared__ float lds[14336];
  const int t = threadIdx.x;

  if (blockIdx.x < 64) {
    // ----------------------------- attention ------------------------------
    const int h  = blockIdx.x >> 2;
    const int l0 = (blockIdx.x & 3) * 32;
    float* ks = lds;            // [128][52]
    float* vs = lds + 6656;

    for (int i = t; i < 128 * 12; i += 512) {
      int m  = i / 12;
      int dd = (i - m * 12) * 4;
      float4 kv = *(const float4*)&proj[(size_t)m * K3E + EMB     + h * DHD + dd];
      float4 vv = *(const float4*)&proj[(size_t)m * K3E + 2 * EMB + h * DHD + dd];
      *(float4*)&ks[m * 52 + dd] = kv;
      *(float4*)&vs[m * 52 + dd] = vv;
    }

    int lr = t >> 4;            // 0..31 row in tile
    int g  = t & 15;
    int lg = l0 + lr;
    const float scale = 0.14433756729740643f;  // 48^-0.5
    float q[48];
#pragma unroll
    for (int jj = 0; jj < 12; jj++) {
      float4 qv = *(const float4*)&proj[(size_t)lg * K3E + h * DHD + jj * 4];
      q[jj*4+0] = qv.x * scale; q[jj*4+1] = qv.y * scale;
      q[jj*4+2] = qv.z * scale; q[jj*4+3] = qv.w * scale;
    }
    __syncthreads();

    float sv[8];
    float smax = -1e30f;
#pragma unroll
    for (int jm = 0; jm < 8; jm++) {
      int m = g + jm * 16;
      float s = 0.0f;
#pragma unroll
      for (int dq = 0; dq < 12; dq++) {
        float4 kv = *(const float4*)&ks[m * 52 + dq * 4];
        s += q[dq*4+0]*kv.x + q[dq*4+1]*kv.y + q[dq*4+2]*kv.z + q[dq*4+3]*kv.w;
      }
      sv[jm] = s;
      smax = fmaxf(smax, s);
    }
#pragma unroll
    for (int off = 1; off < 16; off <<= 1) smax = fmaxf(smax, __shfl_xor(smax, off));
    float ssum = 0.0f;
#pragma unroll
    for (int jm = 0; jm < 8; jm++) { float e = __expf(sv[jm] - smax); sv[jm] = e; ssum += e; }
#pragma unroll
    for (int off = 1; off < 16; off <<= 1) ssum += __shfl_xor(ssum, off);
    float inv = 1.0f / ssum;
#pragma unroll
    for (int jm = 0; jm < 8; jm++) sv[jm] *= inv;

    float acc[48] = {};
#pragma unroll
    for (int jm = 0; jm < 8; jm++) {
      int m = g + jm * 16;
      float p = sv[jm];
#pragma unroll
      for (int dq = 0; dq < 12; dq++) {
        float4 vv = *(const float4*)&vs[m * 52 + dq * 4];
        acc[dq*4+0] += p*vv.x; acc[dq*4+1] += p*vv.y;
        acc[dq*4+2] += p*vv.z; acc[dq*4+3] += p*vv.w;
      }
    }

    {
      float buf[24];
      if (g & 8) {
#pragma unroll
        for (int d = 0; d < 24; d++) buf[d] = acc[d];
      } else {
#pragma unroll
        for (int d = 0; d < 24; d++) buf[d] = acc[d + 24];
      }
#pragma unroll
      for (int d = 0; d < 24; d++) buf[d] = __shfl_xor(buf[d], 8);
      if (g & 8) {
#pragma unroll
        for (int d = 0; d < 24; d++) acc[d] = acc[d + 24] + buf[d];
      } else {
#pragma unroll
        for (int d = 0; d < 24; d++) acc[d] = acc[d] + buf[d];
      }
    }
    {
      float buf[12];
      if (g & 4) {
#pragma unroll
        for (int d = 0; d < 12; d++) buf[d] = acc[d];
      } else {
#pragma unroll
        for (int d = 0; d < 12; d++) buf[d] = acc[d + 12];
      }
#pragma unroll
      for (int d = 0; d < 12; d++) buf[d] = __shfl_xor(buf[d], 4);
      if (g & 4) {
#pragma unroll
        for (int d = 0; d < 12; d++) acc[d] = acc[d + 12] + buf[d];
      } else {
#pragma unroll
        for (int d = 0; d < 12; d++) acc[d] = acc[d] + buf[d];
      }
    }
    {
      float buf[6];
      if (g & 2) {
#pragma unroll
        for (int d = 0; d < 6; d++) buf[d] = acc[d];
      } else {
#pragma unroll
        for (int d = 0; d < 6; d++) buf[d] = acc[d + 6];
      }
#pragma unroll
      for (int d = 0; d < 6; d++) buf[d] = __shfl_xor(buf[d], 2);
      if (g & 2) {
#pragma unroll
        for (int d = 0; d < 6; d++) acc[d] = acc[d + 6] + buf[d];
      } else {
#pragma unroll
        for (int d = 0; d < 6; d++) acc[d] = acc[d] + buf[d];
      }
    }
    {
      float buf[3];
      if (g & 1) {
#pragma unroll
        for (int d = 0; d < 3; d++) buf[d] = acc[d];
      } else {
#pragma unroll
        for (int d = 0; d < 3; d++) buf[d] = acc[d + 3];
      }
#pragma unroll
      for (int d = 0; d < 3; d++) buf[d] = __shfl_xor(buf[d], 1);
      if (g & 1) {
#pragma unroll
        for (int d = 0; d < 3; d++) acc[d] = acc[d + 3] + buf[d];
      } else {
#pragma unroll
        for (int d = 0; d < 3; d++) acc[d] = acc[d] + buf[d];
      }
    }
#pragma unroll
    for (int j = 0; j < 3; j++) {
      ctx[(size_t)lg * EMB + h * DHD + g * 3 + j] = acc[j];
    }

    // -------- arrival: this head's 32-row ctx tile is done -----------------
    __syncthreads();
    if (t == 0) {
      __threadfence();
      __hip_atomic_fetch_add(&flags[l0 >> 5], 1, __ATOMIC_RELAXED,
                             __HIP_MEMORY_SCOPE_AGENT);
    }
  } else {
    // --------------------------- final GEMM -------------------------------
    const int c  = blockIdx.x - 64;
    const int bm = (c >> 2) * 16, bn = (c & 3) * 32;

    if (t == 0) {
      while (__hip_atomic_load(&flags[bm >> 5], __ATOMIC_RELAXED,
                               __HIP_MEMORY_SCOPE_AGENT) < 16)
        __builtin_amdgcn_s_sleep(2);
      __threadfence();
    }
    __syncthreads();

    const int w = t >> 6, l = t & 63;
    const int tx = l & 7, ty = l >> 3;
    const int gm = l & 15, gq = l >> 4;
    const int bl = l & 31, bh = l >> 5;
    const int kbase = w * 96;
    const int AW = w * 1792, BW = AW + 640;

    const float* arow = ctx + (size_t)(bm + gm) * EMB;
    int brow_i = bn + bl; if (brow_i > 99) brow_i = 99;
    const float* brow = wcomb + (size_t)brow_i * EMB;

    float4 aF, bF0, bF1;

#define F_LOAD(s) {                                                          \
    int k0 = kbase + (s) * 16;                                               \
    aF  = *(const float4*)&arow[k0 + gq * 4];                                \
    bF0 = *(const float4*)&brow[k0 + bh * 8 + 0];                            \
    bF1 = *(const float4*)&brow[k0 + bh * 8 + 4]; }

#define F_WRITE(b) {                                                         \
    int Ab = AW + (b) * 320;                                                 \
    lds[Ab + (gq*4+0)*20 + gm] = aF.x;                                       \
    lds[Ab + (gq*4+1)*20 + gm] = aF.y;                                       \
    lds[Ab + (gq*4+2)*20 + gm] = aF.z;                                       \
    lds[Ab + (gq*4+3)*20 + gm] = aF.w;                                       \
    int Bb = BW + (b) * 576;                                                 \
    lds[Bb + (bh*8+0)*36 + bl] = bF0.x; lds[Bb + (bh*8+1)*36 + bl] = bF0.y;  \
    lds[Bb + (bh*8+2)*36 + bl] = bF0.z; lds[Bb + (bh*8+3)*36 + bl] = bF0.w;  \
    lds[Bb + (bh*8+4)*36 + bl] = bF1.x; lds[Bb + (bh*8+5)*36 + bl] = bF1.y;  \
    lds[Bb + (bh*8+6)*36 + bl] = bF1.z; lds[Bb + (bh*8+7)*36 + bl] = bF1.w; }

    float acc[2][4] = {};
    F_LOAD(0); F_WRITE(0);
    for (int s = 0; s < 6; s++) {
      int b = s & 1;
      if (s < 5) F_LOAD(s + 1);
      int Ab = AW + b * 320, Bb = BW + b * 576;
#pragma unroll
      for (int kk = 0; kk < 16; kk++) {
        float2 a  = *(float2*)&lds[Ab + kk * 20 + ty * 2];
        float4 bb = *(float4*)&lds[Bb + kk * 36 + tx * 4];
        acc[0][0] += a.x*bb.x; acc[0][1] += a.x*bb.y; acc[0][2] += a.x*bb.z; acc[0][3] += a.x*bb.w;
        acc[1][0] += a.y*bb.x; acc[1][1] += a.y*bb.y; acc[1][2] += a.y*bb.z; acc[1][3] += a.y*bb.w;
      }
      if (s < 5) F_WRITE(b ^ 1);
    }
#undef F_LOAD
#undef F_WRITE

#pragma unroll
    for (int i = 0; i < 2; i++)
      *(float4*)&lds[AW + (ty*2 + i) * 32 + tx * 4] =
          make_float4(acc[i][0], acc[i][1], acc[i][2], acc[i][3]);
    __syncthreads();
    int m = t >> 5, n = t & 31;
    int col = bn + n;
    if (col < 100) {
      float v = lds[0*1792 + t] + lds[1*1792 + t] + lds[2*1792 + t] + lds[3*1792 + t]
              + lds[4*1792 + t] + lds[5*1792 + t] + lds[6*1792 + t] + lds[7*1792 + t]
              + wsbias[col];
      out[(size_t)(bm + m) * 100 + col] = v;
    }
  }
}

// ---------------------------------------------------------------------------
extern "C" void kernel_launch(void* const* d_in, const int* in_sizes, int n_in,
                              void* d_out, int out_size, void* d_ws, size_t ws_size,
                              hipStream_t stream) {
  const float* lhs   = (const float*)d_in[0];
  // d_in[1] sense_emb: dead — only attn_out[:,0,:] is used downstream.
  const int*   loc   = (const int*)  d_in[2];
  const float* w_in  = (const float*)d_in[3];
  const float* b_in  = (const float*)d_in[4];
  const float* w_out = (const float*)d_in[5];
  const float* b_out = (const float*)d_in[6];
  const float* w_lin = (const float*)d_in[7];
  const float* b_lin = (const float*)d_in[8];
  float* out = (float*)d_out;

  char* ws = (char*)d_ws;
  float* pun    = (float*)(ws);                     // 128*768  = 393216 B
  float* proj   = (float*)(ws + 393216);            // 128*2304 = 1179648 B
  float* ctx    = (float*)(ws + 1572864);           // 128*768  = 393216 B
  float* wcomb  = (float*)(ws + 1966080);           // 100*768  = 307200 B
  float* wsbias = (float*)(ws + 2273280);           // 100 floats
  int*   flags  = (int*)  (ws + 2273680);           // 4 ints

  k0_pun<<<96, 256, 0, stream>>>(lhs, loc, pun, flags);
  k1_gemm_wcomb<<<745, 512, 0, stream>>>(pun, w_in, b_in, proj,
                                         w_lin, w_out, b_out, b_lin,
                                         wcomb, wsbias);
  k23_attn_final<<<96, 512, 0, stream>>>(proj, wcomb, wsbias, ctx, out, flags);
}

// Round 11
// 45.547 us; speedup vs baseline: 1.3077x; 1.3077x over previous
//
#include <hip/hip_runtime.h>

#define SEQ 512
#define EMB 768
#define K3E 2304
#define DHD 48

// ============================================================================
// K0: pun[128,768] = masked gather-mean of lhs rows. 96 x 256 thr. (R5 exact)
// ============================================================================
__global__ __launch_bounds__(256) void k0_pun(
    const float* __restrict__ lhs, const int* __restrict__ loc,
    float* __restrict__ pun)
{
  int id = blockIdx.x * 256 + threadIdx.x;   // 24576 = 128 * 192
  int row = id / 192;
  int ch  = id - row * 192;
  int cnt = 0;
  float4 s = make_float4(0.f, 0.f, 0.f, 0.f);
#pragma unroll
  for (int j = 0; j < 5; j++) {
    int v = loc[row * 5 + j];
    if (v >= 0) {
      float4 wv = *(const float4*)&lhs[((size_t)row * SEQ + v) * EMB + ch * 4];
      s.x += wv.x; s.y += wv.y; s.z += wv.z; s.w += wv.w;
      cnt++;
    }
  }
  float inv = 1.0f / (float)cnt;
  *(float4*)&pun[(size_t)row * EMB + ch * 4] =
      make_float4(s.x * inv, s.y * inv, s.z * inv, s.w * inv);
}

// ============================================================================
// K1: blocks 0..575 proj GEMM (tile 16x32), blocks 576..743 W_comb (16x32).
// R5 geometry; NEW inner loop: wave split into two 32-lane k-halves
// (h2 = lane>>5; half h2 handles k-rows 2*kk+h2), 4m x 8n lane grid,
// 4x4 microtile -> 2 LDS bytes/MAC (was 3). No padding: A stride 16,
// B stride 32 (reads are row-local; write conflicts 4-way = cheap).
// LDS 48KB -> 3 blocks/CU -> one residency round (744 <= 768), 6 waves/SIMD.
// Epilogue: fold halves via shfl_xor(32), then cross-wave LDS reduce.
// ============================================================================
__global__ __launch_bounds__(512, 4) void k1_gemm_wcomb(
    const float* __restrict__ pun, const float* __restrict__ Bw,
    const float* __restrict__ bias, float* __restrict__ C,
    const float* __restrict__ wlin, const float* __restrict__ wout,
    float* __restrict__ wcomb)
{
  __shared__ float lds[12288];           // 8 waves x 1536 (A 2x256 + B 2x512)
  const int t = threadIdx.x;
  const int w = t >> 6, l = t & 63;
  const int h2 = l >> 5;                 // k-half 0/1
  const int tx = l & 7;                  // n-group: n = tx*4..
  const int ty = (l >> 3) & 3;           // m-group: m = ty*4..
  const int gm = l & 15, gq = l >> 4;    // A-staging: m-row, k-quad
  const int bl = l & 31, bh = l >> 5;    // B-staging: n-row, k-half
  const int kbase = w * 96;
  const int AW = w * 1536, BW = AW + 512;

  float4 aF, bF0, bF1;
  float acc[4][4] = {};

#define STAGE_A(b) {                                                         \
    int Ab = AW + (b) * 256;                                                 \
    lds[Ab + (gq*4+0)*16 + gm] = aF.x;                                       \
    lds[Ab + (gq*4+1)*16 + gm] = aF.y;                                       \
    lds[Ab + (gq*4+2)*16 + gm] = aF.z;                                       \
    lds[Ab + (gq*4+3)*16 + gm] = aF.w; }

#define INNER(b) {                                                           \
    int Ab = AW + (b) * 256, Bb = BW + (b) * 512;                            \
    _Pragma("unroll")                                                        \
    for (int kk = 0; kk < 8; kk++) {                                         \
      int row = kk * 2 + h2;                                                 \
      float4 a  = *(float4*)&lds[Ab + row * 16 + ty * 4];                    \
      float4 bb = *(float4*)&lds[Bb + row * 32 + tx * 4];                    \
      acc[0][0] += a.x*bb.x; acc[0][1] += a.x*bb.y;                          \
      acc[0][2] += a.x*bb.z; acc[0][3] += a.x*bb.w;                          \
      acc[1][0] += a.y*bb.x; acc[1][1] += a.y*bb.y;                          \
      acc[1][2] += a.y*bb.z; acc[1][3] += a.y*bb.w;                          \
      acc[2][0] += a.z*bb.x; acc[2][1] += a.z*bb.y;                          \
      acc[2][2] += a.z*bb.z; acc[2][3] += a.z*bb.w;                          \
      acc[3][0] += a.w*bb.x; acc[3][1] += a.w*bb.y;                          \
      acc[3][2] += a.w*bb.z; acc[3][3] += a.w*bb.w;                          \
    } }

#define FOLD_AND_PARTIAL() {                                                 \
    _Pragma("unroll")                                                        \
    for (int i = 0; i < 4; i++) {                                            \
      _Pragma("unroll")                                                      \
      for (int j = 0; j < 4; j++)                                            \
        acc[i][j] += __shfl_xor(acc[i][j], 32);                              \
    }                                                                        \
    if (l < 32) {                                                            \
      _Pragma("unroll")                                                      \
      for (int i = 0; i < 4; i++)                                            \
        *(float4*)&lds[AW + (ty*4 + i) * 32 + tx * 4] =                      \
            make_float4(acc[i][0], acc[i][1], acc[i][2], acc[i][3]);         \
    }                                                                        \
    __syncthreads(); }

  if (blockIdx.x < 576) {
    // ------------------------------ GEMM1 ---------------------------------
    const int c  = blockIdx.x;
    const int bm = (c / 72) * 16, bn = (c % 72) * 32;
    const float* arow = pun + (size_t)(bm + gm) * EMB;
    const float* brow = Bw + (size_t)(bn + bl) * EMB;

#define G_LOAD(s) {                                                          \
    int k0 = kbase + (s) * 16;                                               \
    aF  = *(const float4*)&arow[k0 + gq * 4];                                \
    bF0 = *(const float4*)&brow[k0 + bh * 8 + 0];                            \
    bF1 = *(const float4*)&brow[k0 + bh * 8 + 4]; }

#define G_WRITE(b) {                                                         \
    STAGE_A(b)                                                               \
    int Bb = BW + (b) * 512;                                                 \
    lds[Bb + (bh*8+0)*32 + bl] = bF0.x; lds[Bb + (bh*8+1)*32 + bl] = bF0.y;  \
    lds[Bb + (bh*8+2)*32 + bl] = bF0.z; lds[Bb + (bh*8+3)*32 + bl] = bF0.w;  \
    lds[Bb + (bh*8+4)*32 + bl] = bF1.x; lds[Bb + (bh*8+5)*32 + bl] = bF1.y;  \
    lds[Bb + (bh*8+6)*32 + bl] = bF1.z; lds[Bb + (bh*8+7)*32 + bl] = bF1.w; }

    G_LOAD(0); G_WRITE(0);
    for (int s = 0; s < 6; s++) {
      int b = s & 1;
      if (s < 5) G_LOAD(s + 1);
      INNER(b);
      if (s < 5) G_WRITE(b ^ 1);
    }
#undef G_LOAD
#undef G_WRITE

    FOLD_AND_PARTIAL();
    int m = t >> 5, n = t & 31;
    float v = lds[0*1536 + t] + lds[1*1536 + t] + lds[2*1536 + t] + lds[3*1536 + t]
            + lds[4*1536 + t] + lds[5*1536 + t] + lds[6*1536 + t] + lds[7*1536 + t]
            + bias[bn + n];
    C[(size_t)(bm + m) * K3E + bn + n] = v;
  } else {
    // ------------------------------ W_comb --------------------------------
    const int cc = blockIdx.x - 576;
    const int bm = (cc / 24) * 16, bn = (cc % 24) * 32;
    const int wi = l >> 2;                 // k-row 0..15
    const int j4 = (l & 3) * 8;            // e-offset 0,8,16,24
    int arow_i = bm + gm; if (arow_i > 99) arow_i = 99;
    const float* arow = wlin + (size_t)arow_i * EMB;

#define W_LOAD(s) {                                                          \
    int k0 = kbase + (s) * 16;                                               \
    aF  = *(const float4*)&arow[k0 + gq * 4];                                \
    const float* wr = wout + (size_t)(k0 + wi) * EMB + bn + j4;              \
    bF0 = *(const float4*)&wr[0];                                            \
    bF1 = *(const float4*)&wr[4]; }

#define W_WRITE(b) {                                                         \
    STAGE_A(b)                                                               \
    int Bb = BW + (b) * 512;                                                 \
    *(float4*)&lds[Bb + wi*32 + j4]     = bF0;                               \
    *(float4*)&lds[Bb + wi*32 + j4 + 4] = bF1; }

    W_LOAD(0); W_WRITE(0);
    for (int s = 0; s < 6; s++) {
      int b = s & 1;
      if (s < 5) W_LOAD(s + 1);
      INNER(b);
      if (s < 5) W_WRITE(b ^ 1);
    }
#undef W_LOAD
#undef W_WRITE

    FOLD_AND_PARTIAL();
    int m = t >> 5, n = t & 31;
    if (bm + m < 100) {
      float v = lds[0*1536 + t] + lds[1*1536 + t] + lds[2*1536 + t] + lds[3*1536 + t]
              + lds[4*1536 + t] + lds[5*1536 + t] + lds[6*1536 + t] + lds[7*1536 + t];
      wcomb[(size_t)(bm + m) * EMB + bn + n] = v;
    }
  }
#undef STAGE_A
#undef INNER
#undef FOLD_AND_PARTIAL
}

// ============================================================================
// K2: attention (token 0 only). 128 blocks: h = bx>>3, 16-row l-tile. 256 thr.
// R5 exact.
// ============================================================================
__global__ __launch_bounds__(256) void k2_attn(
    const float* __restrict__ proj, float* __restrict__ ctx)
{
  __shared__ float ks[128][52];
  __shared__ float vs[128][52];
  int h  = blockIdx.x >> 3;
  int l0 = (blockIdx.x & 7) * 16;
  int t  = threadIdx.x;

  for (int i = t; i < 128 * 12; i += 256) {
    int m  = i / 12;
    int dd = (i - m * 12) * 4;
    float4 kv = *(const float4*)&proj[(size_t)m * K3E + EMB     + h * DHD + dd];
    float4 vv = *(const float4*)&proj[(size_t)m * K3E + 2 * EMB + h * DHD + dd];
    *(float4*)&ks[m][dd] = kv;
    *(float4*)&vs[m][dd] = vv;
  }

  int l  = t >> 4;
  int g  = t & 15;
  int lg = l0 + l;
  const float scale = 0.14433756729740643f;  // 48^-0.5
  float q[48];
#pragma unroll
  for (int jj = 0; jj < 12; jj++) {
    float4 qv = *(const float4*)&proj[(size_t)lg * K3E + h * DHD + jj * 4];
    q[jj*4+0] = qv.x * scale; q[jj*4+1] = qv.y * scale;
    q[jj*4+2] = qv.z * scale; q[jj*4+3] = qv.w * scale;
  }
  __syncthreads();

  float sv[8];
  float smax = -1e30f;
#pragma unroll
  for (int jm = 0; jm < 8; jm++) {
    int m = g + jm * 16;
    float s = 0.0f;
#pragma unroll
    for (int dq = 0; dq < 12; dq++) {
      float4 kv = *(const float4*)&ks[m][dq * 4];
      s += q[dq*4+0]*kv.x + q[dq*4+1]*kv.y + q[dq*4+2]*kv.z + q[dq*4+3]*kv.w;
    }
    sv[jm] = s;
    smax = fmaxf(smax, s);
  }
#pragma unroll
  for (int off = 1; off < 16; off <<= 1) smax = fmaxf(smax, __shfl_xor(smax, off));
  float ssum = 0.0f;
#pragma unroll
  for (int jm = 0; jm < 8; jm++) { float e = __expf(sv[jm] - smax); sv[jm] = e; ssum += e; }
#pragma unroll
  for (int off = 1; off < 16; off <<= 1) ssum += __shfl_xor(ssum, off);
  float inv = 1.0f / ssum;
#pragma unroll
  for (int jm = 0; jm < 8; jm++) sv[jm] *= inv;

  float acc[48] = {};
#pragma unroll
  for (int jm = 0; jm < 8; jm++) {
    int m = g + jm * 16;
    float p = sv[jm];
#pragma unroll
    for (int dq = 0; dq < 12; dq++) {
      float4 vv = *(const float4*)&vs[m][dq * 4];
      acc[dq*4+0] += p*vv.x; acc[dq*4+1] += p*vv.y;
      acc[dq*4+2] += p*vv.z; acc[dq*4+3] += p*vv.w;
    }
  }

  {
    float buf[24];
    if (g & 8) {
#pragma unroll
      for (int d = 0; d < 24; d++) buf[d] = acc[d];
    } else {
#pragma unroll
      for (int d = 0; d < 24; d++) buf[d] = acc[d + 24];
    }
#pragma unroll
    for (int d = 0; d < 24; d++) buf[d] = __shfl_xor(buf[d], 8);
    if (g & 8) {
#pragma unroll
      for (int d = 0; d < 24; d++) acc[d] = acc[d + 24] + buf[d];
    } else {
#pragma unroll
      for (int d = 0; d < 24; d++) acc[d] = acc[d] + buf[d];
    }
  }
  {
    float buf[12];
    if (g & 4) {
#pragma unroll
      for (int d = 0; d < 12; d++) buf[d] = acc[d];
    } else {
#pragma unroll
      for (int d = 0; d < 12; d++) buf[d] = acc[d + 12];
    }
#pragma unroll
    for (int d = 0; d < 12; d++) buf[d] = __shfl_xor(buf[d], 4);
    if (g & 4) {
#pragma unroll
      for (int d = 0; d < 12; d++) acc[d] = acc[d + 12] + buf[d];
    } else {
#pragma unroll
      for (int d = 0; d < 12; d++) acc[d] = acc[d] + buf[d];
    }
  }
  {
    float buf[6];
    if (g & 2) {
#pragma unroll
      for (int d = 0; d < 6; d++) buf[d] = acc[d];
    } else {
#pragma unroll
      for (int d = 0; d < 6; d++) buf[d] = acc[d + 6];
    }
#pragma unroll
    for (int d = 0; d < 6; d++) buf[d] = __shfl_xor(buf[d], 2);
    if (g & 2) {
#pragma unroll
      for (int d = 0; d < 6; d++) acc[d] = acc[d + 6] + buf[d];
    } else {
#pragma unroll
      for (int d = 0; d < 6; d++) acc[d] = acc[d] + buf[d];
    }
  }
  {
    float buf[3];
    if (g & 1) {
#pragma unroll
      for (int d = 0; d < 3; d++) buf[d] = acc[d];
    } else {
#pragma unroll
      for (int d = 0; d < 3; d++) buf[d] = acc[d + 3];
    }
#pragma unroll
    for (int d = 0; d < 3; d++) buf[d] = __shfl_xor(buf[d], 1);
    if (g & 1) {
#pragma unroll
      for (int d = 0; d < 3; d++) acc[d] = acc[d + 3] + buf[d];
    } else {
#pragma unroll
      for (int d = 0; d < 3; d++) acc[d] = acc[d] + buf[d];
    }
  }
#pragma unroll
  for (int j = 0; j < 3; j++) {
    ctx[(size_t)lg * EMB + h * DHD + g * 3 + j] = acc[j];
  }
}

// ============================================================================
// K3: res[128,100] = ctx @ W_comb^T + (wlin@b_out + b_lin). R5 exact.
// grid (4,8)=32 blocks, 512 thr = 8 waves, wave K-split 8x96, tile 16x32.
// ============================================================================
__global__ __launch_bounds__(512, 4) void k3_final(
    const float* __restrict__ A, const float* __restrict__ Bw,
    const float* __restrict__ wlin, const float* __restrict__ bout,
    const float* __restrict__ blin, float* __restrict__ C)
{
  __shared__ float lds[14368];  // staging 14336 + sbias 32
  const int t = threadIdx.x;
  const int w = t >> 6, l = t & 63;
  const int bm = blockIdx.y * 16, bn = blockIdx.x * 32;
  const int tx = l & 7, ty = l >> 3;
  const int gm = l & 15, gq = l >> 4;
  const int bl = l & 31, bh = l >> 5;
  const int kbase = w * 96;
  const int AW = w * 1792, BW = AW + 640;

  if (t < 256) {   // bias_comb for this block's 32 cols
    int col = bn + (t >> 3);
    int ks  = (t & 7) * 96;
    float p = 0.f;
    if (col < 100) {
      const float* wr = wlin + (size_t)col * EMB + ks;
#pragma unroll
      for (int j = 0; j < 24; j++) {
        float4 wv = *(const float4*)&wr[j * 4];
        float4 bv = *(const float4*)&bout[ks + j * 4];
        p += wv.x*bv.x + wv.y*bv.y + wv.z*bv.z + wv.w*bv.w;
      }
    }
    p += __shfl_xor(p, 1); p += __shfl_xor(p, 2); p += __shfl_xor(p, 4);
    if ((t & 7) == 0) lds[14336 + (t >> 3)] = p + (col < 100 ? blin[col] : 0.f);
  }

  const float* arow = A + (size_t)(bm + gm) * EMB;
  int brow_i = bn + bl; if (brow_i > 99) brow_i = 99;
  const float* brow = Bw + (size_t)brow_i * EMB;

  float4 aF, bF0, bF1;

#define F_LOAD(s) {                                                          \
    int k0 = kbase + (s) * 16;                                               \
    aF  = *(const float4*)&arow[k0 + gq * 4];                                \
    bF0 = *(const float4*)&brow[k0 + bh * 8 + 0];                            \
    bF1 = *(const float4*)&brow[k0 + bh * 8 + 4]; }

#define F_WRITE(b) {                                                         \
    int Ab = AW + (b) * 320;                                                 \
    lds[Ab + (gq*4+0)*20 + gm] = aF.x;                                       \
    lds[Ab + (gq*4+1)*20 + gm] = aF.y;                                       \
    lds[Ab + (gq*4+2)*20 + gm] = aF.z;                                       \
    lds[Ab + (gq*4+3)*20 + gm] = aF.w;                                       \
    int Bb = BW + (b) * 576;                                                 \
    lds[Bb + (bh*8+0)*36 + bl] = bF0.x; lds[Bb + (bh*8+1)*36 + bl] = bF0.y;  \
    lds[Bb + (bh*8+2)*36 + bl] = bF0.z; lds[Bb + (bh*8+3)*36 + bl] = bF0.w;  \
    lds[Bb + (bh*8+4)*36 + bl] = bF1.x; lds[Bb + (bh*8+5)*36 + bl] = bF1.y;  \
    lds[Bb + (bh*8+6)*36 + bl] = bF1.z; lds[Bb + (bh*8+7)*36 + bl] = bF1.w; }

  float acc[2][4] = {};
  F_LOAD(0); F_WRITE(0);
  for (int s = 0; s < 6; s++) {
    int b = s & 1;
    if (s < 5) F_LOAD(s + 1);
    int Ab = AW + b * 320, Bb = BW + b * 576;
#pragma unroll
    for (int kk = 0; kk < 16; kk++) {
      float2 a  = *(float2*)&lds[Ab + kk * 20 + ty * 2];
      float4 bb = *(float4*)&lds[Bb + kk * 36 + tx * 4];
      acc[0][0] += a.x*bb.x; acc[0][1] += a.x*bb.y; acc[0][2] += a.x*bb.z; acc[0][3] += a.x*bb.w;
      acc[1][0] += a.y*bb.x; acc[1][1] += a.y*bb.y; acc[1][2] += a.y*bb.z; acc[1][3] += a.y*bb.w;
    }
    if (s < 5) F_WRITE(b ^ 1);
  }
#undef F_LOAD
#undef F_WRITE

#pragma unroll
  for (int i = 0; i < 2; i++)
    *(float4*)&lds[AW + (ty*2 + i) * 32 + tx * 4] =
        make_float4(acc[i][0], acc[i][1], acc[i][2], acc[i][3]);
  __syncthreads();
  int m = t >> 5, n = t & 31;
  int col = bn + n;
  if (col < 100) {
    float v = lds[0*1792 + t] + lds[1*1792 + t] + lds[2*1792 + t] + lds[3*1792 + t]
            + lds[4*1792 + t] + lds[5*1792 + t] + lds[6*1792 + t] + lds[7*1792 + t]
            + lds[14336 + n];
    C[(size_t)(bm + m) * 100 + col] = v;
  }
}

// ---------------------------------------------------------------------------
extern "C" void kernel_launch(void* const* d_in, const int* in_sizes, int n_in,
                              void* d_out, int out_size, void* d_ws, size_t ws_size,
                              hipStream_t stream) {
  const float* lhs   = (const float*)d_in[0];
  // d_in[1] sense_emb: dead — only attn_out[:,0,:] is used downstream.
  const int*   loc   = (const int*)  d_in[2];
  const float* w_in  = (const float*)d_in[3];
  const float* b_in  = (const float*)d_in[4];
  const float* w_out = (const float*)d_in[5];
  const float* b_out = (const float*)d_in[6];
  const float* w_lin = (const float*)d_in[7];
  const float* b_lin = (const float*)d_in[8];
  float* out = (float*)d_out;

  char* ws = (char*)d_ws;
  float* pun   = (float*)(ws);                     // 128*768  = 393216 B
  float* proj  = (float*)(ws + 393216);            // 128*2304 = 1179648 B
  float* ctx   = (float*)(ws + 1572864);           // 128*768  = 393216 B
  float* wcomb = (float*)(ws + 1966080);           // 100*768  = 307200 B

  k0_pun<<<96, 256, 0, stream>>>(lhs, loc, pun);
  k1_gemm_wcomb<<<744, 512, 0, stream>>>(pun, w_in, b_in, proj,
                                         w_lin, w_out, wcomb);
  k2_attn<<<128, 256, 0, stream>>>(proj, ctx);
  k3_final<<<dim3(4, 8), 512, 0, stream>>>(ctx, wcomb, w_lin, b_out, b_lin, out);
}